// Round 5
// baseline (323.576 us; speedup 1.0000x reference)
//
#include <hip/hip_runtime.h>

#define BATCH 4
#define NHEADS 3
#define SEQ 2048
#define HDIM 256
#define EMBD 768
#define MTOT (BATCH*SEQ)          // 8192
#define WSZ (NHEADS*EMBD*HDIM)    // 589824 per projection weight

typedef unsigned short u16x8 __attribute__((ext_vector_type(8)));
typedef unsigned short u16x4 __attribute__((ext_vector_type(4)));
typedef __bf16 bf16x8 __attribute__((ext_vector_type(8)));
typedef float fx4 __attribute__((ext_vector_type(4)));

__device__ __forceinline__ unsigned short f2bf(float x) {
    union { float f; unsigned int u; } v; v.f = x;
    unsigned int r = v.u + 0x7fffu + ((v.u >> 16) & 1u);
    return (unsigned short)(r >> 16);
}

__device__ __forceinline__ fx4 mfma16(u16x8 a, u16x8 b, fx4 c) {
    return __builtin_amdgcn_mfma_f32_16x16x32_bf16(
        __builtin_bit_cast(bf16x8, a), __builtin_bit_cast(bf16x8, b), c, 0, 0, 0);
}

// async global->LDS, 16B per lane; LDS dest = wave-uniform base + lane*16.
__device__ __forceinline__ void gl_lds16(const unsigned short* g, unsigned short* l) {
    __builtin_amdgcn_global_load_lds(
        (const __attribute__((address_space(1))) unsigned int*)g,
        (__attribute__((address_space(3))) unsigned int*)l, 16, 0, 0);
}

// attn work schedule per (b,h): entries qt*4+kc, kc in {0,1}=k-chunk (qt>=16,
// writes partials), kc=3 = whole causal range (qt<16, writes heads directly).
__device__ const unsigned char attn_sched[48] = {
    124,125, 63, 120,121, 116,117, 59, 112,113, 108,109, 55, 104,105,
    100,101, 51,  96, 97,  92, 93, 47,  88, 89,  84, 85, 43,  80, 81,
     76, 77, 39,  72, 73,  68, 69, 35,  64, 65,  31, 27, 23, 19, 15,
     11,  7,  3
};

// ---------------------------------------------------------------------------
// Kernel 1: cast A inputs fp32->bf16 + weight cast/transpose.
// Abf[z][m][e] bf16;  Wt[t][n=h*256+f][e] bf16;  Wot[n][k] bf16.
// ---------------------------------------------------------------------------
__global__ __launch_bounds__(256) void castAw_kernel(
    const float* __restrict__ Ak, const float* __restrict__ Av,
    const float* __restrict__ Aq,
    const float* __restrict__ Wk, const float* __restrict__ Wv,
    const float* __restrict__ Wq, const float* __restrict__ Wo,
    unsigned short* __restrict__ Abf, unsigned short* __restrict__ Wt,
    unsigned short* __restrict__ Wot)
{
    __shared__ float tile[64][65];
    int bx = blockIdx.x;
    if (bx < 9216) {            // A cast: 3 * 8192*768 elems, 8 per thread
        int e = (bx * 256 + threadIdx.x) * 8;
        int t = e / (MTOT * EMBD);
        int r = e - t * (MTOT * EMBD);
        const float* A = (t == 0) ? Ak : (t == 1) ? Av : Aq;
        const fx4* s = (const fx4*)(A + r);
        fx4 v0 = s[0], v1 = s[1];
        u16x8 o;
        o[0]=f2bf(v0[0]); o[1]=f2bf(v0[1]); o[2]=f2bf(v0[2]); o[3]=f2bf(v0[3]);
        o[4]=f2bf(v1[0]); o[5]=f2bf(v1[1]); o[6]=f2bf(v1[2]); o[7]=f2bf(v1[3]);
        *(u16x8*)(Abf + e) = o;
        return;
    }
    int z = bx - 9216;          // weight transpose via 64x64 LDS tile
    const float* src; unsigned short* dst;
    int src_ld, dst_ld, e0, f0;
    if (z < 432) {
        int t = z / 144, rem = z - t * 144;
        int h = rem / 48, tl = rem - h * 48;
        e0 = (tl % 12) * 64; f0 = (tl / 12) * 64;
        const float* W = (t == 0) ? Wk : (t == 1) ? Wv : Wq;
        src = W + h * 768 * 256; src_ld = 256;
        dst = Wt + t * WSZ + h * 256 * 768; dst_ld = 768;
    } else {
        int zz = z - 432;
        e0 = (zz % 12) * 64; f0 = (zz / 12) * 64;
        src = Wo; src_ld = 768;
        dst = Wot; dst_ld = 768;
    }
    int tx = threadIdx.x & 63, ty4 = threadIdx.x >> 6;
    #pragma unroll
    for (int i = 0; i < 16; ++i) {
        int r = ty4 + i * 4;
        tile[r][tx] = src[(e0 + r) * src_ld + f0 + tx];
    }
    __syncthreads();
    #pragma unroll
    for (int i = 0; i < 16; ++i) {
        int r = ty4 + i * 4;
        dst[(f0 + r) * dst_ld + e0 + tx] = f2bf(tile[tx][r]);
    }
}

// ---------------------------------------------------------------------------
// Kernel 2: projection GEMM, m97 structure (unchanged from R4).
// ---------------------------------------------------------------------------
__global__ __launch_bounds__(256) void proj_kernel(
    const unsigned short* __restrict__ Abf, const unsigned short* __restrict__ Wt,
    unsigned short* __restrict__ Kg, unsigned short* __restrict__ Vg,
    unsigned short* __restrict__ Qg)
{
    __shared__ alignas(16) unsigned short S[17408];
    unsigned short* As = S;
    unsigned short* Bs = S + 8192;

    int z = blockIdx.z;
    const unsigned short* A = Abf + z * (MTOT * EMBD);
    int m0 = blockIdx.x * 128;
    int h = blockIdx.y >> 1, fbase = (blockIdx.y & 1) * 128;
    const unsigned short* W = Wt + z * WSZ + (h * 256 + fbase) * EMBD;

    int tid = threadIdx.x;
    int w = tid >> 6, ln = tid & 63;
    int lane16 = ln & 15, quad = ln >> 4;
    int mw = (w & 1) * 64, nw = (w >> 1) * 64;

    fx4 acc[4][4];
    #pragma unroll
    for (int i = 0; i < 4; ++i)
        #pragma unroll
        for (int j = 0; j < 4; ++j) acc[i][j] = (fx4){0.f, 0.f, 0.f, 0.f};

    int c0 = tid, c1 = tid + 256;
    int r0 = c0 >> 2, s0_ = (c0 & 3) * 8;
    int r1 = c1 >> 2, s1_ = (c1 & 3) * 8;
    const unsigned short* Ag0 = A + (m0 + r0) * EMBD + s0_;
    const unsigned short* Ag1 = A + (m0 + r1) * EMBD + s1_;
    const unsigned short* Wg0 = W + r0 * EMBD + s0_;
    const unsigned short* Wg1 = W + r1 * EMBD + s1_;

    for (int kb = 0; kb < EMBD; kb += 32) {
        __syncthreads();
        gl_lds16(Ag0 + kb, &As[c0 * 8]);
        gl_lds16(Ag1 + kb, &As[c1 * 8]);
        gl_lds16(Wg0 + kb, &Bs[c0 * 8]);
        gl_lds16(Wg1 + kb, &Bs[c1 * 8]);
        __syncthreads();

        u16x8 af[4], bf[4];
        #pragma unroll
        for (int i = 0; i < 4; ++i) {
            af[i] = *(const u16x8*)&As[(mw + i * 16 + lane16) * 32 + quad * 8];
            bf[i] = *(const u16x8*)&Bs[(nw + i * 16 + lane16) * 32 + quad * 8];
        }
        #pragma unroll
        for (int i = 0; i < 4; ++i)
            #pragma unroll
            for (int j = 0; j < 4; ++j)
                acc[i][j] = mfma16(af[i], bf[j], acc[i][j]);
    }

    __syncthreads();
    int b = m0 >> 11, sq0 = m0 & 2047;

    if (z == 1) {
        #pragma unroll
        for (int i = 0; i < 4; ++i)
            #pragma unroll
            for (int j = 0; j < 4; ++j) {
                int fl = nw + j * 16 + lane16;
                int ml = mw + i * 16 + quad * 4;
                u16x4 pk;
                pk[0] = f2bf(acc[i][j][0]); pk[1] = f2bf(acc[i][j][1]);
                pk[2] = f2bf(acc[i][j][2]); pk[3] = f2bf(acc[i][j][3]);
                *(u16x4*)&S[fl * 136 + ml] = pk;
            }
        __syncthreads();
        int fl = tid >> 1, mseg = (tid & 1) * 64;
        const unsigned short* srcp = &S[fl * 136 + mseg];
        unsigned short* dstp = Vg + ((b * NHEADS + h) * HDIM + fbase + fl) * SEQ + sq0 + mseg;
        #pragma unroll
        for (int c = 0; c < 8; ++c)
            *(u16x8*)(dstp + c * 8) = *(const u16x8*)(srcp + c * 8);
    } else {
        #pragma unroll
        for (int i = 0; i < 4; ++i)
            #pragma unroll
            for (int j = 0; j < 4; ++j) {
                int fl = nw + j * 16 + lane16;
                int ml = mw + i * 16 + quad * 4;
                #pragma unroll
                for (int r = 0; r < 4; ++r)
                    S[(ml + r) * 136 + fl] = f2bf(acc[i][j][r]);
            }
        __syncthreads();
        unsigned short* dst0 = (z == 0) ? Kg : Qg;
        int ml = tid >> 1, fseg = (tid & 1) * 64;
        const unsigned short* srcp = &S[ml * 136 + fseg];
        unsigned short* dstp = dst0 + ((b * NHEADS + h) * SEQ + sq0 + ml) * HDIM + fbase + fseg;
        #pragma unroll
        for (int c = 0; c < 8; ++c)
            *(u16x8*)(dstp + c * 8) = *(const u16x8*)(srcp + c * 8);
    }
}

// ---------------------------------------------------------------------------
// Kernel 3: causal attention. Block = 4 waves x 16 q-rows, k-tile = 64 keys,
// K/V staged via global_load_lds (64 KB LDS, 2 blocks/CU), one drain per
// 64-key iteration (2x MFMA per barrier vs R4). No-max softmax, shfl
// P-transform, split-k (qt>=16 -> 2 chunks, additive fp32 partials).
// ---------------------------------------------------------------------------
__global__ __launch_bounds__(256) void attn_kernel(
    const unsigned short* __restrict__ Kg, const unsigned short* __restrict__ Vg,
    const unsigned short* __restrict__ Qg, unsigned short* __restrict__ heads,
    float* __restrict__ Opart, float* __restrict__ Lpart)
{
    __shared__ alignas(16) unsigned short Ks[64 * 256];   // [k=64][f=256]
    __shared__ alignas(16) unsigned short Vs[256 * 64];   // [f=256][k=64]

    int bx = blockIdx.x;
    int bh = bx % 12;
    int ent = attn_sched[bx / 12];
    int qt = ent >> 2, kc = ent & 3;
    int tid = threadIdx.x;
    int w = tid >> 6, ln = tid & 63;
    int lane16 = ln & 15, quad = ln >> 4;
    int q0w = qt * 64 + w * 16;

    const unsigned short* Kbase = Kg + bh * (SEQ * HDIM);
    const unsigned short* Vbase = Vg + bh * (SEQ * HDIM);  // [f][s]
    const unsigned short* Qbase = Qg + bh * (SEQ * HDIM);

    u16x8 qf[8];   // B-operand: Q[q0w+lane16][c*32 + quad*8 + j]
    {
        const unsigned short* qrow = Qbase + (q0w + lane16) * HDIM + quad * 8;
        #pragma unroll
        for (int c = 0; c < 8; ++c) qf[c] = *(const u16x8*)(qrow + c * 32);
    }

    fx4 o[16];
    #pragma unroll
    for (int i = 0; i < 16; ++i) o[i] = (fx4){0.f, 0.f, 0.f, 0.f};
    float lsum = 0.f;

    const float Cs2 = 0.03188010519640429f;  // log2(e)/sqrt(2048)

    // 64-key tiles: q-tile qt needs tiles 0..qt (inclusive)
    int t0, t1;
    if (kc == 3) { t0 = 0; t1 = qt + 1; }
    else         { int half = (qt + 1) >> 1;
                   t0 = kc ? half : 0; t1 = kc ? qt + 1 : half; }

    // staging maps (chunk = 16B): Ks row-major [64][256]; Vs [256][64]
    const unsigned short* kgp = Kbase + (tid >> 5) * HDIM + (tid & 31) * 8;
    const unsigned short* vgp = Vbase + (tid >> 3) * SEQ + (tid & 7) * 8;
    unsigned short* ksl = &Ks[tid * 8];
    unsigned short* vsl = &Vs[tid * 8];

    for (int kt = t0; kt < t1; ++kt) {
        int k0 = kt * 64;
        __syncthreads();   // prior tile's LDS reads complete
        #pragma unroll
        for (int j = 0; j < 8; ++j)
            gl_lds16(kgp + (k0 + j * 8) * HDIM, ksl + j * 2048);
        #pragma unroll
        for (int j = 0; j < 8; ++j)
            gl_lds16(vgp + j * 32 * SEQ + k0, vsl + j * 2048);
        __syncthreads();   // staged (vmcnt drained before barrier)

        // S^T = K * Q^T : 4 key-subtiles of 16
        fx4 sacc[4];
        #pragma unroll
        for (int ks = 0; ks < 4; ++ks) sacc[ks] = (fx4){0.f,0.f,0.f,0.f};
        #pragma unroll
        for (int c = 0; c < 8; ++c) {
            #pragma unroll
            for (int ks = 0; ks < 4; ++ks) {
                u16x8 kf = *(const u16x8*)&Ks[(ks * 16 + lane16) * 256 + c * 32 + quad * 8];
                sacc[ks] = mfma16(kf, qf[c], sacc[ks]);
            }
        }

        // p = exp2(s*Cs2) with causal mask; lane owns q = q0w+lane16,
        // key = k0 + ks*16 + quad*4 + r
        float p[4][4];
        int q = q0w + lane16;
        #pragma unroll
        for (int ks = 0; ks < 4; ++ks)
            #pragma unroll
            for (int r = 0; r < 4; ++r) {
                int ka_ = k0 + ks * 16 + quad * 4 + r;
                float e = exp2f(sacc[ks][r] * Cs2);
                p[ks][r] = (ka_ <= q) ? e : 0.f;
                lsum += p[ks][r];
            }

        // two 32-key halves: shfl C->A transform + PV
        #pragma unroll
        for (int hh = 0; hh < 2; ++hh) {
            u16x8 pf;
            #pragma unroll
            for (int j = 0; j < 8; ++j) {
                int srcLane = ((((quad << 1) + (j >> 2)) & 3) << 4) | lane16;
                float v0 = __shfl(p[2 * hh][j & 3], srcLane, 64);
                float v1 = __shfl(p[2 * hh + 1][j & 3], srcLane, 64);
                pf[j] = f2bf(quad >= 2 ? v1 : v0);
            }
            #pragma unroll
            for (int ft = 0; ft < 16; ++ft) {
                u16x8 vf = *(const u16x8*)&Vs[(ft * 16 + lane16) * 64 + hh * 32 + quad * 8];
                o[ft] = mfma16(pf, vf, o[ft]);
            }
        }
    }

    lsum += __shfl_xor(lsum, 16, 64);
    lsum += __shfl_xor(lsum, 32, 64);

    if (kc == 3) {
        float linv = 1.f / lsum;
        float inv[4];
        #pragma unroll
        for (int r = 0; r < 4; ++r) inv[r] = __shfl(linv, quad * 4 + r, 64);
        int b = bh / 3, h = bh - (bh / 3) * 3;
        unsigned short* hp = heads + (b * SEQ + q0w + quad * 4) * EMBD + h * HDIM + lane16;
        #pragma unroll
        for (int ft = 0; ft < 16; ++ft)
            #pragma unroll
            for (int r = 0; r < 4; ++r)
                hp[r * EMBD + ft * 16] = f2bf(o[ft][r] * inv[r]);
    } else {
        int slot = (bh * 16 + (qt - 16)) * 2 + kc;
        float* Op = Opart + slot * 16384 + (w * 16 + quad * 4) * 256 + lane16;
        #pragma unroll
        for (int ft = 0; ft < 16; ++ft)
            #pragma unroll
            for (int r = 0; r < 4; ++r)
                Op[r * 256 + ft * 16] = o[ft][r];
        if (quad == 0) Lpart[slot * 64 + w * 16 + lane16] = lsum;
    }
}

// ---------------------------------------------------------------------------
// Kernel 4: combine split-k partials (qt>=16), normalize, write heads bf16.
// ---------------------------------------------------------------------------
__global__ __launch_bounds__(256) void combine_kernel(
    const float* __restrict__ Opart, const float* __restrict__ Lpart,
    unsigned short* __restrict__ heads)
{
    int t = blockIdx.x;              // bh*16 + (qt-16)
    int bh = t >> 4, qt = (t & 15) + 16;
    int s0 = t * 2, s1 = s0 + 1;
    int tid = threadIdx.x;
    int row = tid >> 2, fseg = (tid & 3) * 64;
    float l = Lpart[s0 * 64 + row] + Lpart[s1 * 64 + row];
    float inv = 1.f / l;
    const fx4* O0 = (const fx4*)(Opart + s0 * 16384 + row * 256 + fseg);
    const fx4* O1 = (const fx4*)(Opart + s1 * 16384 + row * 256 + fseg);
    int b = bh / 3, h = bh - (bh / 3) * 3;
    unsigned short* hp = heads + (b * SEQ + qt * 64 + row) * EMBD + h * HDIM + fseg;
    #pragma unroll
    for (int i = 0; i < 16; ++i) {
        fx4 v = O0[i] + O1[i];
        u16x4 pk;
        pk[0] = f2bf(v[0] * inv); pk[1] = f2bf(v[1] * inv);
        pk[2] = f2bf(v[2] * inv); pk[3] = f2bf(v[3] * inv);
        *(u16x4*)(hp + i * 4) = pk;
    }
}

// ---------------------------------------------------------------------------
// Kernel 5: output projection, m97 structure (unchanged from R4).
// ---------------------------------------------------------------------------
__global__ __launch_bounds__(256) void outproj_kernel(
    const unsigned short* __restrict__ A, const unsigned short* __restrict__ Wot,
    const float* __restrict__ bo, float* __restrict__ out)
{
    __shared__ alignas(16) unsigned short S[16384];
    unsigned short* As = S;
    unsigned short* Bs = S + 8192;

    int m0 = blockIdx.x * 128, n0 = blockIdx.y * 128;
    int tid = threadIdx.x;
    int w = tid >> 6, ln = tid & 63;
    int lane16 = ln & 15, quad = ln >> 4;
    int mw = (w & 1) * 64, nw = (w >> 1) * 64;

    fx4 acc[4][4];
    #pragma unroll
    for (int i = 0; i < 4; ++i)
        #pragma unroll
        for (int j = 0; j < 4; ++j) acc[i][j] = (fx4){0.f, 0.f, 0.f, 0.f};

    int c0 = tid, c1 = tid + 256;
    int r0 = c0 >> 2, s0_ = (c0 & 3) * 8;
    int r1 = c1 >> 2, s1_ = (c1 & 3) * 8;
    const unsigned short* Ag0 = A + (m0 + r0) * EMBD + s0_;
    const unsigned short* Ag1 = A + (m0 + r1) * EMBD + s1_;
    const unsigned short* Wg0 = Wot + (n0 + r0) * EMBD + s0_;
    const unsigned short* Wg1 = Wot + (n0 + r1) * EMBD + s1_;

    for (int kb = 0; kb < EMBD; kb += 32) {
        __syncthreads();
        gl_lds16(Ag0 + kb, &As[c0 * 8]);
        gl_lds16(Ag1 + kb, &As[c1 * 8]);
        gl_lds16(Wg0 + kb, &Bs[c0 * 8]);
        gl_lds16(Wg1 + kb, &Bs[c1 * 8]);
        __syncthreads();

        u16x8 af[4], bf[4];
        #pragma unroll
        for (int i = 0; i < 4; ++i) {
            af[i] = *(const u16x8*)&As[(mw + i * 16 + lane16) * 32 + quad * 8];
            bf[i] = *(const u16x8*)&Bs[(nw + i * 16 + lane16) * 32 + quad * 8];
        }
        #pragma unroll
        for (int i = 0; i < 4; ++i)
            #pragma unroll
            for (int j = 0; j < 4; ++j)
                acc[i][j] = mfma16(af[i], bf[j], acc[i][j]);
    }

    #pragma unroll
    for (int i = 0; i < 4; ++i) {
        int mb = m0 + mw + i * 16 + quad * 4;
        #pragma unroll
        for (int j = 0; j < 4; ++j) {
            int n = n0 + nw + j * 16 + lane16;
            float bias = bo[n];
            #pragma unroll
            for (int r = 0; r < 4; ++r)
                out[(mb + r) * EMBD + n] = acc[i][j][r] + bias;
        }
    }
}

// ---------------------------------------------------------------------------
extern "C" void kernel_launch(void* const* d_in, const int* in_sizes, int n_in,
                              void* d_out, int out_size, void* d_ws, size_t ws_size,
                              hipStream_t stream) {
    const float* Ak = (const float*)d_in[0];
    const float* Av = (const float*)d_in[1];
    const float* Aq = (const float*)d_in[2];
    const float* Wk = (const float*)d_in[3];
    const float* Wv = (const float*)d_in[4];
    const float* Wq = (const float*)d_in[5];
    const float* Wo = (const float*)d_in[6];
    const float* bo = (const float*)d_in[7];
    float* out = (float*)d_out;

    char* base = (char*)d_ws;
    unsigned short* Wt    = (unsigned short*)(base);               // 3.54 MB
    unsigned short* Wot   = (unsigned short*)(base + 3538944);     // 1.18 MB
    unsigned short* Abf   = (unsigned short*)(base + 4718592);     // 37.75 MB
    unsigned short* Kg    = (unsigned short*)(base + 42467328);    // 12.58 MB
    unsigned short* Vg    = (unsigned short*)(base + 55050240);    // 12.58 MB
    unsigned short* Qg    = (unsigned short*)(base + 67633152);    // 12.58 MB
    unsigned short* heads = (unsigned short*)(base + 80216064);    // 12.58 MB
    // split-k partials overlay the Abf region (Abf dead after proj_kernel)
    float* Opart = (float*)(base + 4718592);                       // 25.17 MB
    float* Lpart = (float*)(base + 4718592 + 25165824);            // 98 KB

    castAw_kernel<<<dim3(9792), dim3(256), 0, stream>>>(
        Ak, Av, Aq, Wk, Wv, Wq, Wo, Abf, Wt, Wot);
    proj_kernel<<<dim3(64, 6, 3), dim3(256), 0, stream>>>(
        Abf, Wt, Kg, Vg, Qg);
    attn_kernel<<<dim3(576), dim3(256), 0, stream>>>(
        Kg, Vg, Qg, heads, Opart, Lpart);
    combine_kernel<<<dim3(192), dim3(256), 0, stream>>>(Opart, Lpart, heads);
    outproj_kernel<<<dim3(64, 6), dim3(256), 0, stream>>>(heads, Wot, bo, out);
}

// Round 6
// 312.766 us; speedup vs baseline: 1.0346x; 1.0346x over previous
//
#include <hip/hip_runtime.h>

#define BATCH 4
#define NHEADS 3
#define SEQ 2048
#define HDIM 256
#define EMBD 768
#define MTOT (BATCH*SEQ)          // 8192
#define WSZ (NHEADS*EMBD*HDIM)    // 589824 per projection weight

typedef unsigned short u16x8 __attribute__((ext_vector_type(8)));
typedef unsigned short u16x4 __attribute__((ext_vector_type(4)));
typedef __bf16 bf16x8 __attribute__((ext_vector_type(8)));
typedef float fx4 __attribute__((ext_vector_type(4)));

__device__ __forceinline__ unsigned short f2bf(float x) {
    union { float f; unsigned int u; } v; v.f = x;
    unsigned int r = v.u + 0x7fffu + ((v.u >> 16) & 1u);
    return (unsigned short)(r >> 16);
}

__device__ __forceinline__ fx4 mfma16(u16x8 a, u16x8 b, fx4 c) {
    return __builtin_amdgcn_mfma_f32_16x16x32_bf16(
        __builtin_bit_cast(bf16x8, a), __builtin_bit_cast(bf16x8, b), c, 0, 0, 0);
}

// async global->LDS, 16B per lane; LDS dest = wave-uniform base + lane*16.
__device__ __forceinline__ void gl_lds16(const unsigned short* g, unsigned short* l) {
    __builtin_amdgcn_global_load_lds(
        (const __attribute__((address_space(1))) unsigned int*)g,
        (__attribute__((address_space(3))) unsigned int*)l, 16, 0, 0);
}

// attn work schedule per (b,h): entries qt*4+kc, kc in {0,1}=k-chunk (qt>=16,
// writes partials), kc=3 = whole causal range (qt<16, writes heads directly).
__device__ const unsigned char attn_sched[48] = {
    124,125, 63, 120,121, 116,117, 59, 112,113, 108,109, 55, 104,105,
    100,101, 51,  96, 97,  92, 93, 47,  88, 89,  84, 85, 43,  80, 81,
     76, 77, 39,  72, 73,  68, 69, 35,  64, 65,  31, 27, 23, 19, 15,
     11,  7,  3
};

// ---------------------------------------------------------------------------
// Kernel 1: cast A inputs fp32->bf16 + weight cast/transpose.
// Abf[z][m][e] bf16;  Wt[t][n=h*256+f][e] bf16;  Wot[n][k] bf16.
// ---------------------------------------------------------------------------
__global__ __launch_bounds__(256) void castAw_kernel(
    const float* __restrict__ Ak, const float* __restrict__ Av,
    const float* __restrict__ Aq,
    const float* __restrict__ Wk, const float* __restrict__ Wv,
    const float* __restrict__ Wq, const float* __restrict__ Wo,
    unsigned short* __restrict__ Abf, unsigned short* __restrict__ Wt,
    unsigned short* __restrict__ Wot)
{
    __shared__ float tile[64][65];
    int bx = blockIdx.x;
    if (bx < 9216) {            // A cast: 3 * 8192*768 elems, 8 per thread
        int e = (bx * 256 + threadIdx.x) * 8;
        int t = e / (MTOT * EMBD);
        int r = e - t * (MTOT * EMBD);
        const float* A = (t == 0) ? Ak : (t == 1) ? Av : Aq;
        const fx4* s = (const fx4*)(A + r);
        fx4 v0 = s[0], v1 = s[1];
        u16x8 o;
        o[0]=f2bf(v0[0]); o[1]=f2bf(v0[1]); o[2]=f2bf(v0[2]); o[3]=f2bf(v0[3]);
        o[4]=f2bf(v1[0]); o[5]=f2bf(v1[1]); o[6]=f2bf(v1[2]); o[7]=f2bf(v1[3]);
        *(u16x8*)(Abf + e) = o;
        return;
    }
    int z = bx - 9216;          // weight transpose via 64x64 LDS tile
    const float* src; unsigned short* dst;
    int src_ld, dst_ld, e0, f0;
    if (z < 432) {
        int t = z / 144, rem = z - t * 144;
        int h = rem / 48, tl = rem - h * 48;
        e0 = (tl % 12) * 64; f0 = (tl / 12) * 64;
        const float* W = (t == 0) ? Wk : (t == 1) ? Wv : Wq;
        src = W + h * 768 * 256; src_ld = 256;
        dst = Wt + t * WSZ + h * 256 * 768; dst_ld = 768;
    } else {
        int zz = z - 432;
        e0 = (zz % 12) * 64; f0 = (zz / 12) * 64;
        src = Wo; src_ld = 768;
        dst = Wot; dst_ld = 768;
    }
    int tx = threadIdx.x & 63, ty4 = threadIdx.x >> 6;
    #pragma unroll
    for (int i = 0; i < 16; ++i) {
        int r = ty4 + i * 4;
        tile[r][tx] = src[(e0 + r) * src_ld + f0 + tx];
    }
    __syncthreads();
    #pragma unroll
    for (int i = 0; i < 16; ++i) {
        int r = ty4 + i * 4;
        dst[(f0 + r) * dst_ld + e0 + tx] = f2bf(tile[tx][r]);
    }
}

// ---------------------------------------------------------------------------
// Kernel 2: projection GEMM, m97 structure + XOR-swizzled staging.
// As/Bs [128][32] shorts = 512 16B-units; unit u of row r stored at
// slot u ^ ((r>>1)&3)  -> frag reads 2-way (free) instead of 8-way.
// ---------------------------------------------------------------------------
__global__ __launch_bounds__(256) void proj_kernel(
    const unsigned short* __restrict__ Abf, const unsigned short* __restrict__ Wt,
    unsigned short* __restrict__ Kg, unsigned short* __restrict__ Vg,
    unsigned short* __restrict__ Qg)
{
    __shared__ alignas(16) unsigned short S[17408];
    unsigned short* As = S;
    unsigned short* Bs = S + 8192;

    int z = blockIdx.z;
    const unsigned short* A = Abf + z * (MTOT * EMBD);
    int m0 = blockIdx.x * 128;
    int h = blockIdx.y >> 1, fbase = (blockIdx.y & 1) * 128;
    const unsigned short* W = Wt + z * WSZ + (h * 256 + fbase) * EMBD;

    int tid = threadIdx.x;
    int w = tid >> 6, ln = tid & 63;
    int lane16 = ln & 15, quad = ln >> 4;
    int mw = (w & 1) * 64, nw = (w >> 1) * 64;

    fx4 acc[4][4];
    #pragma unroll
    for (int i = 0; i < 4; ++i)
        #pragma unroll
        for (int j = 0; j < 4; ++j) acc[i][j] = (fx4){0.f, 0.f, 0.f, 0.f};

    // staging chunks (16B): LDS unit U = c -> row U>>2, slot U&3,
    // global unit fetched = slot ^ ((row>>1)&3)
    int c0 = tid, c1 = tid + 256;
    int r0 = c0 >> 2, s0_ = ((c0 & 3) ^ ((c0 >> 3) & 3)) * 8;
    int r1 = c1 >> 2, s1_ = ((c1 & 3) ^ ((c1 >> 3) & 3)) * 8;
    const unsigned short* Ag0 = A + (m0 + r0) * EMBD + s0_;
    const unsigned short* Ag1 = A + (m0 + r1) * EMBD + s1_;
    const unsigned short* Wg0 = W + r0 * EMBD + s0_;
    const unsigned short* Wg1 = W + r1 * EMBD + s1_;

    int fsw = (quad ^ ((lane16 >> 1) & 3)) * 8;   // frag-read swizzled offset

    for (int kb = 0; kb < EMBD; kb += 32) {
        __syncthreads();
        gl_lds16(Ag0 + kb, &As[c0 * 8]);
        gl_lds16(Ag1 + kb, &As[c1 * 8]);
        gl_lds16(Wg0 + kb, &Bs[c0 * 8]);
        gl_lds16(Wg1 + kb, &Bs[c1 * 8]);
        __syncthreads();

        u16x8 af[4], bf[4];
        #pragma unroll
        for (int i = 0; i < 4; ++i) {
            af[i] = *(const u16x8*)&As[(mw + i * 16 + lane16) * 32 + fsw];
            bf[i] = *(const u16x8*)&Bs[(nw + i * 16 + lane16) * 32 + fsw];
        }
        #pragma unroll
        for (int i = 0; i < 4; ++i)
            #pragma unroll
            for (int j = 0; j < 4; ++j)
                acc[i][j] = mfma16(af[i], bf[j], acc[i][j]);
    }

    __syncthreads();
    int b = m0 >> 11, sq0 = m0 & 2047;

    if (z == 1) {
        #pragma unroll
        for (int i = 0; i < 4; ++i)
            #pragma unroll
            for (int j = 0; j < 4; ++j) {
                int fl = nw + j * 16 + lane16;
                int ml = mw + i * 16 + quad * 4;
                u16x4 pk;
                pk[0] = f2bf(acc[i][j][0]); pk[1] = f2bf(acc[i][j][1]);
                pk[2] = f2bf(acc[i][j][2]); pk[3] = f2bf(acc[i][j][3]);
                *(u16x4*)&S[fl * 136 + ml] = pk;
            }
        __syncthreads();
        int fl = tid >> 1, mseg = (tid & 1) * 64;
        const unsigned short* srcp = &S[fl * 136 + mseg];
        unsigned short* dstp = Vg + ((b * NHEADS + h) * HDIM + fbase + fl) * SEQ + sq0 + mseg;
        #pragma unroll
        for (int c = 0; c < 8; ++c)
            *(u16x8*)(dstp + c * 8) = *(const u16x8*)(srcp + c * 8);
    } else {
        #pragma unroll
        for (int i = 0; i < 4; ++i)
            #pragma unroll
            for (int j = 0; j < 4; ++j) {
                int fl = nw + j * 16 + lane16;
                int ml = mw + i * 16 + quad * 4;
                #pragma unroll
                for (int r = 0; r < 4; ++r)
                    S[(ml + r) * 136 + fl] = f2bf(acc[i][j][r]);
            }
        __syncthreads();
        unsigned short* dst0 = (z == 0) ? Kg : Qg;
        int ml = tid >> 1, fseg = (tid & 1) * 64;
        const unsigned short* srcp = &S[ml * 136 + fseg];
        unsigned short* dstp = dst0 + ((b * NHEADS + h) * SEQ + sq0 + ml) * HDIM + fbase + fseg;
        #pragma unroll
        for (int c = 0; c < 8; ++c)
            *(u16x8*)(dstp + c * 8) = *(const u16x8*)(srcp + c * 8);
    }
}

// ---------------------------------------------------------------------------
// Kernel 3: causal attention, k-tile=64, global_load_lds staging with
// XOR-swizzled unit placement: unit u of row r lives at slot u ^ (r&7).
// Frag reads hit all 8 four-bank groups (2-way = free) instead of 16-way.
// No-max softmax, shfl P-transform, split-k (qt>=16 -> 2 additive chunks).
// ---------------------------------------------------------------------------
__global__ __launch_bounds__(256) void attn_kernel(
    const unsigned short* __restrict__ Kg, const unsigned short* __restrict__ Vg,
    const unsigned short* __restrict__ Qg, unsigned short* __restrict__ heads,
    float* __restrict__ Opart, float* __restrict__ Lpart)
{
    __shared__ alignas(16) unsigned short Ks[64 * 256];   // [k=64][f=256] swizzled
    __shared__ alignas(16) unsigned short Vs[256 * 64];   // [f=256][k=64] swizzled

    int bx = blockIdx.x;
    int bh = bx % 12;
    int ent = attn_sched[bx / 12];
    int qt = ent >> 2, kc = ent & 3;
    int tid = threadIdx.x;
    int w = tid >> 6, ln = tid & 63;
    int lane16 = ln & 15, quad = ln >> 4;
    int q0w = qt * 64 + w * 16;

    const unsigned short* Kbase = Kg + bh * (SEQ * HDIM);
    const unsigned short* Vbase = Vg + bh * (SEQ * HDIM);  // [f][s]
    const unsigned short* Qbase = Qg + bh * (SEQ * HDIM);

    u16x8 qf[8];   // B-operand: Q[q0w+lane16][c*32 + quad*8 + j]
    {
        const unsigned short* qrow = Qbase + (q0w + lane16) * HDIM + quad * 8;
        #pragma unroll
        for (int c = 0; c < 8; ++c) qf[c] = *(const u16x8*)(qrow + c * 32);
    }

    fx4 o[16];
    #pragma unroll
    for (int i = 0; i < 16; ++i) o[i] = (fx4){0.f, 0.f, 0.f, 0.f};
    float lsum = 0.f;

    const float Cs2 = 0.03188010519640429f;  // log2(e)/sqrt(2048)

    int t0, t1;
    if (kc == 3) { t0 = 0; t1 = qt + 1; }
    else         { int half = (qt + 1) >> 1;
                   t0 = kc ? half : 0; t1 = kc ? qt + 1 : half; }

    // K staging: LDS unit U = tid + j*256 -> row (tid>>5)+j*8, slot tid&31;
    // fetch global unit (tid&31) ^ (row&7); (row&7) == (tid>>5) for all j.
    const unsigned short* kgp = Kbase + (tid >> 5) * HDIM
                              + (((tid & 31) ^ (tid >> 5)) * 8);
    // V staging: LDS unit U -> row (tid>>3)+j*32, slot tid&7;
    // fetch global unit (tid&7) ^ ((tid>>3)&7) (j*32 = 0 mod 8).
    const unsigned short* vgp = Vbase + (tid >> 3) * SEQ
                              + (((tid & 7) ^ ((tid >> 3) & 7)) * 8);
    unsigned short* ksl = &Ks[tid * 8];
    unsigned short* vsl = &Vs[tid * 8];

    int ksw = lane16 & 7;    // frag-read row-swizzle field

    for (int kt = t0; kt < t1; ++kt) {
        int k0 = kt * 64;
        __syncthreads();   // prior tile's LDS reads complete
        #pragma unroll
        for (int j = 0; j < 8; ++j)
            gl_lds16(kgp + (k0 + j * 8) * HDIM, ksl + j * 2048);
        #pragma unroll
        for (int j = 0; j < 8; ++j)
            gl_lds16(vgp + j * 32 * SEQ + k0, vsl + j * 2048);
        __syncthreads();   // staged (vmcnt drained before barrier)

        // S^T = K * Q^T : 4 key-subtiles of 16
        fx4 sacc[4];
        #pragma unroll
        for (int ks = 0; ks < 4; ++ks) sacc[ks] = (fx4){0.f,0.f,0.f,0.f};
        #pragma unroll
        for (int c = 0; c < 8; ++c) {
            #pragma unroll
            for (int ks = 0; ks < 4; ++ks) {
                u16x8 kf = *(const u16x8*)&Ks[(ks * 16 + lane16) * 256
                                              + (((c * 4 + quad) ^ ksw) << 3)];
                sacc[ks] = mfma16(kf, qf[c], sacc[ks]);
            }
        }

        float p[4][4];
        int q = q0w + lane16;
        #pragma unroll
        for (int ks = 0; ks < 4; ++ks)
            #pragma unroll
            for (int r = 0; r < 4; ++r) {
                int ka_ = k0 + ks * 16 + quad * 4 + r;
                float e = exp2f(sacc[ks][r] * Cs2);
                p[ks][r] = (ka_ <= q) ? e : 0.f;
                lsum += p[ks][r];
            }

        #pragma unroll
        for (int hh = 0; hh < 2; ++hh) {
            u16x8 pf;
            #pragma unroll
            for (int j = 0; j < 8; ++j) {
                int srcLane = ((((quad << 1) + (j >> 2)) & 3) << 4) | lane16;
                float v0 = __shfl(p[2 * hh][j & 3], srcLane, 64);
                float v1 = __shfl(p[2 * hh + 1][j & 3], srcLane, 64);
                pf[j] = f2bf(quad >= 2 ? v1 : v0);
            }
            #pragma unroll
            for (int ft = 0; ft < 16; ++ft) {
                u16x8 vf = *(const u16x8*)&Vs[(ft * 16 + lane16) * 64
                                              + (((hh * 4 + quad) ^ ksw) << 3)];
                o[ft] = mfma16(pf, vf, o[ft]);
            }
        }
    }

    lsum += __shfl_xor(lsum, 16, 64);
    lsum += __shfl_xor(lsum, 32, 64);

    if (kc == 3) {
        float linv = 1.f / lsum;
        float inv[4];
        #pragma unroll
        for (int r = 0; r < 4; ++r) inv[r] = __shfl(linv, quad * 4 + r, 64);
        int b = bh / 3, h = bh - (bh / 3) * 3;
        unsigned short* hp = heads + (b * SEQ + q0w + quad * 4) * EMBD + h * HDIM + lane16;
        #pragma unroll
        for (int ft = 0; ft < 16; ++ft)
            #pragma unroll
            for (int r = 0; r < 4; ++r)
                hp[r * EMBD + ft * 16] = f2bf(o[ft][r] * inv[r]);
    } else {
        int slot = (bh * 16 + (qt - 16)) * 2 + kc;
        float* Op = Opart + slot * 16384 + (w * 16 + quad * 4) * 256 + lane16;
        #pragma unroll
        for (int ft = 0; ft < 16; ++ft)
            #pragma unroll
            for (int r = 0; r < 4; ++r)
                Op[r * 256 + ft * 16] = o[ft][r];
        if (quad == 0) Lpart[slot * 64 + w * 16 + lane16] = lsum;
    }
}

// ---------------------------------------------------------------------------
// Kernel 4: combine split-k partials (qt>=16), normalize, write heads bf16.
// ---------------------------------------------------------------------------
__global__ __launch_bounds__(256) void combine_kernel(
    const float* __restrict__ Opart, const float* __restrict__ Lpart,
    unsigned short* __restrict__ heads)
{
    int t = blockIdx.x;              // bh*16 + (qt-16)
    int bh = t >> 4, qt = (t & 15) + 16;
    int s0 = t * 2, s1 = s0 + 1;
    int tid = threadIdx.x;
    int row = tid >> 2, fseg = (tid & 3) * 64;
    float l = Lpart[s0 * 64 + row] + Lpart[s1 * 64 + row];
    float inv = 1.f / l;
    const fx4* O0 = (const fx4*)(Opart + s0 * 16384 + row * 256 + fseg);
    const fx4* O1 = (const fx4*)(Opart + s1 * 16384 + row * 256 + fseg);
    int b = bh / 3, h = bh - (bh / 3) * 3;
    unsigned short* hp = heads + (b * SEQ + qt * 64 + row) * EMBD + h * HDIM + fseg;
    #pragma unroll
    for (int i = 0; i < 16; ++i) {
        fx4 v = O0[i] + O1[i];
        u16x4 pk;
        pk[0] = f2bf(v[0] * inv); pk[1] = f2bf(v[1] * inv);
        pk[2] = f2bf(v[2] * inv); pk[3] = f2bf(v[3] * inv);
        *(u16x4*)(hp + i * 4) = pk;
    }
}

// ---------------------------------------------------------------------------
// Kernel 5: output projection, m97 structure + swizzled staging.
// ---------------------------------------------------------------------------
__global__ __launch_bounds__(256) void outproj_kernel(
    const unsigned short* __restrict__ A, const unsigned short* __restrict__ Wot,
    const float* __restrict__ bo, float* __restrict__ out)
{
    __shared__ alignas(16) unsigned short S[16384];
    unsigned short* As = S;
    unsigned short* Bs = S + 8192;

    int m0 = blockIdx.x * 128, n0 = blockIdx.y * 128;
    int tid = threadIdx.x;
    int w = tid >> 6, ln = tid & 63;
    int lane16 = ln & 15, quad = ln >> 4;
    int mw = (w & 1) * 64, nw = (w >> 1) * 64;

    fx4 acc[4][4];
    #pragma unroll
    for (int i = 0; i < 4; ++i)
        #pragma unroll
        for (int j = 0; j < 4; ++j) acc[i][j] = (fx4){0.f, 0.f, 0.f, 0.f};

    int c0 = tid, c1 = tid + 256;
    int r0 = c0 >> 2, s0_ = ((c0 & 3) ^ ((c0 >> 3) & 3)) * 8;
    int r1 = c1 >> 2, s1_ = ((c1 & 3) ^ ((c1 >> 3) & 3)) * 8;
    const unsigned short* Ag0 = A + (m0 + r0) * EMBD + s0_;
    const unsigned short* Ag1 = A + (m0 + r1) * EMBD + s1_;
    const unsigned short* Wg0 = Wot + (n0 + r0) * EMBD + s0_;
    const unsigned short* Wg1 = Wot + (n0 + r1) * EMBD + s1_;

    int fsw = (quad ^ ((lane16 >> 1) & 3)) * 8;

    for (int kb = 0; kb < EMBD; kb += 32) {
        __syncthreads();
        gl_lds16(Ag0 + kb, &As[c0 * 8]);
        gl_lds16(Ag1 + kb, &As[c1 * 8]);
        gl_lds16(Wg0 + kb, &Bs[c0 * 8]);
        gl_lds16(Wg1 + kb, &Bs[c1 * 8]);
        __syncthreads();

        u16x8 af[4], bf[4];
        #pragma unroll
        for (int i = 0; i < 4; ++i) {
            af[i] = *(const u16x8*)&As[(mw + i * 16 + lane16) * 32 + fsw];
            bf[i] = *(const u16x8*)&Bs[(nw + i * 16 + lane16) * 32 + fsw];
        }
        #pragma unroll
        for (int i = 0; i < 4; ++i)
            #pragma unroll
            for (int j = 0; j < 4; ++j)
                acc[i][j] = mfma16(af[i], bf[j], acc[i][j]);
    }

    #pragma unroll
    for (int i = 0; i < 4; ++i) {
        int mb = m0 + mw + i * 16 + quad * 4;
        #pragma unroll
        for (int j = 0; j < 4; ++j) {
            int n = n0 + nw + j * 16 + lane16;
            float bias = bo[n];
            #pragma unroll
            for (int r = 0; r < 4; ++r)
                out[(mb + r) * EMBD + n] = acc[i][j][r] + bias;
        }
    }
}

// ---------------------------------------------------------------------------
extern "C" void kernel_launch(void* const* d_in, const int* in_sizes, int n_in,
                              void* d_out, int out_size, void* d_ws, size_t ws_size,
                              hipStream_t stream) {
    const float* Ak = (const float*)d_in[0];
    const float* Av = (const float*)d_in[1];
    const float* Aq = (const float*)d_in[2];
    const float* Wk = (const float*)d_in[3];
    const float* Wv = (const float*)d_in[4];
    const float* Wq = (const float*)d_in[5];
    const float* Wo = (const float*)d_in[6];
    const float* bo = (const float*)d_in[7];
    float* out = (float*)d_out;

    char* base = (char*)d_ws;
    unsigned short* Wt    = (unsigned short*)(base);               // 3.54 MB
    unsigned short* Wot   = (unsigned short*)(base + 3538944);     // 1.18 MB
    unsigned short* Abf   = (unsigned short*)(base + 4718592);     // 37.75 MB
    unsigned short* Kg    = (unsigned short*)(base + 42467328);    // 12.58 MB
    unsigned short* Vg    = (unsigned short*)(base + 55050240);    // 12.58 MB
    unsigned short* Qg    = (unsigned short*)(base + 67633152);    // 12.58 MB
    unsigned short* heads = (unsigned short*)(base + 80216064);    // 12.58 MB
    // split-k partials overlay the Abf region (Abf dead after proj_kernel)
    float* Opart = (float*)(base + 4718592);                       // 25.17 MB
    float* Lpart = (float*)(base + 4718592 + 25165824);            // 98 KB

    castAw_kernel<<<dim3(9792), dim3(256), 0, stream>>>(
        Ak, Av, Aq, Wk, Wv, Wq, Wo, Abf, Wt, Wot);
    proj_kernel<<<dim3(64, 6, 3), dim3(256), 0, stream>>>(
        Abf, Wt, Kg, Vg, Qg);
    attn_kernel<<<dim3(576), dim3(256), 0, stream>>>(
        Kg, Vg, Qg, heads, Opart, Lpart);
    combine_kernel<<<dim3(192), dim3(256), 0, stream>>>(Opart, Lpart, heads);
    outproj_kernel<<<dim3(64, 6), dim3(256), 0, stream>>>(heads, Wot, bo, out);
}

// Round 7
// 307.062 us; speedup vs baseline: 1.0538x; 1.0186x over previous
//
#include <hip/hip_runtime.h>

#define BATCH 4
#define NHEADS 3
#define SEQ 2048
#define HDIM 256
#define EMBD 768
#define MTOT (BATCH*SEQ)          // 8192
#define WSZ (NHEADS*EMBD*HDIM)    // 589824 per projection weight

typedef unsigned short u16x8 __attribute__((ext_vector_type(8)));
typedef unsigned short u16x4 __attribute__((ext_vector_type(4)));
typedef __bf16 bf16x8 __attribute__((ext_vector_type(8)));
typedef float fx4 __attribute__((ext_vector_type(4)));

__device__ __forceinline__ unsigned short f2bf(float x) {
    union { float f; unsigned int u; } v; v.f = x;
    unsigned int r = v.u + 0x7fffu + ((v.u >> 16) & 1u);
    return (unsigned short)(r >> 16);
}

__device__ __forceinline__ fx4 mfma16(u16x8 a, u16x8 b, fx4 c) {
    return __builtin_amdgcn_mfma_f32_16x16x32_bf16(
        __builtin_bit_cast(bf16x8, a), __builtin_bit_cast(bf16x8, b), c, 0, 0, 0);
}

// async global->LDS, 16B per lane; LDS dest = wave-uniform base + lane*16.
__device__ __forceinline__ void gl_lds16(const unsigned short* g, unsigned short* l) {
    __builtin_amdgcn_global_load_lds(
        (const __attribute__((address_space(1))) unsigned int*)g,
        (__attribute__((address_space(3))) unsigned int*)l, 16, 0, 0);
}

// attn work schedule per (b,h): entries qt*4+kc, kc in {0,1}=k-chunk (qt>=16,
// writes partials), kc=3 = whole causal range (qt<16, writes heads directly).
__device__ const unsigned char attn_sched[48] = {
    124,125, 63, 120,121, 116,117, 59, 112,113, 108,109, 55, 104,105,
    100,101, 51,  96, 97,  92, 93, 47,  88, 89,  84, 85, 43,  80, 81,
     76, 77, 39,  72, 73,  68, 69, 35,  64, 65,  31, 27, 23, 19, 15,
     11,  7,  3
};

// ---------------------------------------------------------------------------
// Kernel 1: cast A inputs fp32->bf16 + weight cast/transpose (unchanged).
// ---------------------------------------------------------------------------
__global__ __launch_bounds__(256) void castAw_kernel(
    const float* __restrict__ Ak, const float* __restrict__ Av,
    const float* __restrict__ Aq,
    const float* __restrict__ Wk, const float* __restrict__ Wv,
    const float* __restrict__ Wq, const float* __restrict__ Wo,
    unsigned short* __restrict__ Abf, unsigned short* __restrict__ Wt,
    unsigned short* __restrict__ Wot)
{
    __shared__ float tile[64][65];
    int bx = blockIdx.x;
    if (bx < 9216) {            // A cast: 3 * 8192*768 elems, 8 per thread
        int e = (bx * 256 + threadIdx.x) * 8;
        int t = e / (MTOT * EMBD);
        int r = e - t * (MTOT * EMBD);
        const float* A = (t == 0) ? Ak : (t == 1) ? Av : Aq;
        const fx4* s = (const fx4*)(A + r);
        fx4 v0 = s[0], v1 = s[1];
        u16x8 o;
        o[0]=f2bf(v0[0]); o[1]=f2bf(v0[1]); o[2]=f2bf(v0[2]); o[3]=f2bf(v0[3]);
        o[4]=f2bf(v1[0]); o[5]=f2bf(v1[1]); o[6]=f2bf(v1[2]); o[7]=f2bf(v1[3]);
        *(u16x8*)(Abf + e) = o;
        return;
    }
    int z = bx - 9216;          // weight transpose via 64x64 LDS tile
    const float* src; unsigned short* dst;
    int src_ld, dst_ld, e0, f0;
    if (z < 432) {
        int t = z / 144, rem = z - t * 144;
        int h = rem / 48, tl = rem - h * 48;
        e0 = (tl % 12) * 64; f0 = (tl / 12) * 64;
        const float* W = (t == 0) ? Wk : (t == 1) ? Wv : Wq;
        src = W + h * 768 * 256; src_ld = 256;
        dst = Wt + t * WSZ + h * 256 * 768; dst_ld = 768;
    } else {
        int zz = z - 432;
        e0 = (zz % 12) * 64; f0 = (zz / 12) * 64;
        src = Wo; src_ld = 768;
        dst = Wot; dst_ld = 768;
    }
    int tx = threadIdx.x & 63, ty4 = threadIdx.x >> 6;
    #pragma unroll
    for (int i = 0; i < 16; ++i) {
        int r = ty4 + i * 4;
        tile[r][tx] = src[(e0 + r) * src_ld + f0 + tx];
    }
    __syncthreads();
    #pragma unroll
    for (int i = 0; i < 16; ++i) {
        int r = ty4 + i * 4;
        dst[(f0 + r) * dst_ld + e0 + tx] = f2bf(tile[tx][r]);
    }
}

// ---------------------------------------------------------------------------
// Kernel 2: projection GEMM, BARRIER-FREE K-loop.
// Block 256(M) x 64(N), 4 waves each 64x64. Weights LDS-resident in two
// 48 KB phases (XOR-swizzled for conflict-free frag reads); A-fragments
// loaded global->VGPR with distance-1 prefetch. No __syncthreads in the
// inner loop -> compiler emits fine-grained vmcnt/lgkmcnt, loads pipeline
// across iterations. grid (32 m, 12 n = head*4+ftile, 3 z). 3 blocks/CU.
// ---------------------------------------------------------------------------
__global__ __launch_bounds__(256, 3) void proj_kernel(
    const unsigned short* __restrict__ Abf, const unsigned short* __restrict__ Wt,
    unsigned short* __restrict__ Kg, unsigned short* __restrict__ Vg,
    unsigned short* __restrict__ Qg)
{
    __shared__ alignas(16) unsigned short Bs[24576];   // 48 KiB, phase/epilogue

    int z = blockIdx.z;
    const unsigned short* A = Abf + z * (MTOT * EMBD);
    int m0 = blockIdx.x * 256;
    int nb = blockIdx.y;
    int h = nb >> 2, fbase = (nb & 3) * 64;
    const unsigned short* W = Wt + z * WSZ + (h * 256 + fbase) * EMBD; // 64 x 768

    int tid = threadIdx.x;
    int w = tid >> 6, ln = tid & 63;
    int lane16 = ln & 15, quad = ln >> 4;
    int mw = w * 64;

    fx4 acc[4][4];
    #pragma unroll
    for (int i = 0; i < 4; ++i)
        #pragma unroll
        for (int j = 0; j < 4; ++j) acc[i][j] = (fx4){0.f, 0.f, 0.f, 0.f};

    const unsigned short* Ap = A + (m0 + mw + lane16) * EMBD + quad * 8;

    u16x8 afc[4], afn[4];
    #pragma unroll
    for (int i = 0; i < 4; ++i) afc[i] = *(const u16x8*)(Ap + i * 16 * EMBD);

    int bsw = lane16 & 7;

    #pragma unroll
    for (int ph = 0; ph < 2; ++ph) {
        __syncthreads();   // previous phase's Bs reads complete
        // stage 64 rows x 384 k (3072 16B-units, 12/thread), swizzled:
        // unit at LDS slot s of row r holds global unit (s&~7)|((s&7)^(r&7))
        #pragma unroll
        for (int jj = 0; jj < 12; ++jj) {
            int U = jj * 256 + tid;
            int row = U / 48;
            int slot = U - row * 48;
            int gu = (slot & ~7) | ((slot & 7) ^ (row & 7));
            gl_lds16(W + row * EMBD + ph * 384 + gu * 8, &Bs[U * 8]);
        }
        __syncthreads();   // phase staged (one-time drain)

        #pragma unroll
        for (int kk = 0; kk < 12; ++kk) {
            int kbn = ph * 384 + kk * 32 + 32;
            if (kbn < EMBD) {   // prefetch next A-frags (static branch)
                #pragma unroll
                for (int i = 0; i < 4; ++i)
                    afn[i] = *(const u16x8*)(Ap + i * 16 * EMBD + kbn);
            }
            #pragma unroll
            for (int j = 0; j < 4; ++j) {
                int u = kk * 4 + quad;
                int slot = (u & ~7) | ((u & 7) ^ bsw);
                u16x8 bf = *(const u16x8*)&Bs[((j * 16 + lane16) * 48 + slot) * 8];
                #pragma unroll
                for (int i = 0; i < 4; ++i)
                    acc[i][j] = mfma16(afc[i], bf, acc[i][j]);
            }
            if (kbn < EMBD) {
                #pragma unroll
                for (int i = 0; i < 4; ++i) afc[i] = afn[i];
            }
        }
    }

    int b = m0 >> 11, sq0 = m0 & 2047;

    if (z == 1) {
        // V: LDS transpose [64 f][256 m + 8 pad], coalesced [f][s] stores
        __syncthreads();
        #pragma unroll
        for (int i = 0; i < 4; ++i)
            #pragma unroll
            for (int j = 0; j < 4; ++j) {
                int fl = j * 16 + lane16;
                int ml = mw + i * 16 + quad * 4;
                u16x4 pk;
                pk[0] = f2bf(acc[i][j][0]); pk[1] = f2bf(acc[i][j][1]);
                pk[2] = f2bf(acc[i][j][2]); pk[3] = f2bf(acc[i][j][3]);
                *(u16x4*)&Bs[fl * 264 + ml] = pk;
            }
        __syncthreads();
        int fl = tid >> 2, seg = (tid & 3) * 64;
        const unsigned short* sp = &Bs[fl * 264 + seg];
        unsigned short* dp = Vg + ((size_t)(b * NHEADS + h) * HDIM + fbase + fl) * SEQ
                           + sq0 + seg;
        #pragma unroll
        for (int c = 0; c < 8; ++c)
            *(u16x8*)(dp + c * 8) = *(const u16x8*)(sp + c * 8);
    } else {
        // K/Q: two passes over 32-f halves via LDS [256 m][40], coalesced rows
        unsigned short* dst0 = (z == 0) ? Kg : Qg;
        #pragma unroll
        for (int q = 0; q < 2; ++q) {
            __syncthreads();
            #pragma unroll
            for (int i = 0; i < 4; ++i)
                #pragma unroll
                for (int j2 = 0; j2 < 2; ++j2) {
                    int jj = q * 2 + j2;
                    int row = mw + i * 16 + quad * 4;
                    int col = j2 * 16 + lane16;
                    #pragma unroll
                    for (int r = 0; r < 4; ++r)
                        Bs[(row + r) * 40 + col] = f2bf(acc[i][jj][r]);
                }
            __syncthreads();
            const unsigned short* sp = &Bs[tid * 40];
            unsigned short* dp = dst0 + ((size_t)(b * NHEADS + h) * SEQ + sq0 + tid) * HDIM
                               + fbase + q * 32;
            #pragma unroll
            for (int c = 0; c < 4; ++c)
                *(u16x8*)(dp + c * 8) = *(const u16x8*)(sp + c * 8);
        }
    }
}

// ---------------------------------------------------------------------------
// Kernel 3: causal attention (unchanged from R6 — swizzled gl_lds staging).
// ---------------------------------------------------------------------------
__global__ __launch_bounds__(256) void attn_kernel(
    const unsigned short* __restrict__ Kg, const unsigned short* __restrict__ Vg,
    const unsigned short* __restrict__ Qg, unsigned short* __restrict__ heads,
    float* __restrict__ Opart, float* __restrict__ Lpart)
{
    __shared__ alignas(16) unsigned short Ks[64 * 256];
    __shared__ alignas(16) unsigned short Vs[256 * 64];

    int bx = blockIdx.x;
    int bh = bx % 12;
    int ent = attn_sched[bx / 12];
    int qt = ent >> 2, kc = ent & 3;
    int tid = threadIdx.x;
    int w = tid >> 6, ln = tid & 63;
    int lane16 = ln & 15, quad = ln >> 4;
    int q0w = qt * 64 + w * 16;

    const unsigned short* Kbase = Kg + bh * (SEQ * HDIM);
    const unsigned short* Vbase = Vg + bh * (SEQ * HDIM);  // [f][s]
    const unsigned short* Qbase = Qg + bh * (SEQ * HDIM);

    u16x8 qf[8];
    {
        const unsigned short* qrow = Qbase + (q0w + lane16) * HDIM + quad * 8;
        #pragma unroll
        for (int c = 0; c < 8; ++c) qf[c] = *(const u16x8*)(qrow + c * 32);
    }

    fx4 o[16];
    #pragma unroll
    for (int i = 0; i < 16; ++i) o[i] = (fx4){0.f, 0.f, 0.f, 0.f};
    float lsum = 0.f;

    const float Cs2 = 0.03188010519640429f;  // log2(e)/sqrt(2048)

    int t0, t1;
    if (kc == 3) { t0 = 0; t1 = qt + 1; }
    else         { int half = (qt + 1) >> 1;
                   t0 = kc ? half : 0; t1 = kc ? qt + 1 : half; }

    const unsigned short* kgp = Kbase + (tid >> 5) * HDIM
                              + (((tid & 31) ^ (tid >> 5)) * 8);
    const unsigned short* vgp = Vbase + (tid >> 3) * SEQ
                              + (((tid & 7) ^ ((tid >> 3) & 7)) * 8);
    unsigned short* ksl = &Ks[tid * 8];
    unsigned short* vsl = &Vs[tid * 8];

    int ksw = lane16 & 7;

    for (int kt = t0; kt < t1; ++kt) {
        int k0 = kt * 64;
        __syncthreads();
        #pragma unroll
        for (int j = 0; j < 8; ++j)
            gl_lds16(kgp + (k0 + j * 8) * HDIM, ksl + j * 2048);
        #pragma unroll
        for (int j = 0; j < 8; ++j)
            gl_lds16(vgp + j * 32 * SEQ + k0, vsl + j * 2048);
        __syncthreads();

        fx4 sacc[4];
        #pragma unroll
        for (int ks = 0; ks < 4; ++ks) sacc[ks] = (fx4){0.f,0.f,0.f,0.f};
        #pragma unroll
        for (int c = 0; c < 8; ++c) {
            #pragma unroll
            for (int ks = 0; ks < 4; ++ks) {
                u16x8 kf = *(const u16x8*)&Ks[(ks * 16 + lane16) * 256
                                              + (((c * 4 + quad) ^ ksw) << 3)];
                sacc[ks] = mfma16(kf, qf[c], sacc[ks]);
            }
        }

        float p[4][4];
        int q = q0w + lane16;
        #pragma unroll
        for (int ks = 0; ks < 4; ++ks)
            #pragma unroll
            for (int r = 0; r < 4; ++r) {
                int ka_ = k0 + ks * 16 + quad * 4 + r;
                float e = exp2f(sacc[ks][r] * Cs2);
                p[ks][r] = (ka_ <= q) ? e : 0.f;
                lsum += p[ks][r];
            }

        #pragma unroll
        for (int hh = 0; hh < 2; ++hh) {
            u16x8 pf;
            #pragma unroll
            for (int j = 0; j < 8; ++j) {
                int srcLane = ((((quad << 1) + (j >> 2)) & 3) << 4) | lane16;
                float v0 = __shfl(p[2 * hh][j & 3], srcLane, 64);
                float v1 = __shfl(p[2 * hh + 1][j & 3], srcLane, 64);
                pf[j] = f2bf(quad >= 2 ? v1 : v0);
            }
            #pragma unroll
            for (int ft = 0; ft < 16; ++ft) {
                u16x8 vf = *(const u16x8*)&Vs[(ft * 16 + lane16) * 64
                                              + (((hh * 4 + quad) ^ ksw) << 3)];
                o[ft] = mfma16(pf, vf, o[ft]);
            }
        }
    }

    lsum += __shfl_xor(lsum, 16, 64);
    lsum += __shfl_xor(lsum, 32, 64);

    if (kc == 3) {
        float linv = 1.f / lsum;
        float inv[4];
        #pragma unroll
        for (int r = 0; r < 4; ++r) inv[r] = __shfl(linv, quad * 4 + r, 64);
        int b = bh / 3, h = bh - (bh / 3) * 3;
        unsigned short* hp = heads + (b * SEQ + q0w + quad * 4) * EMBD + h * HDIM + lane16;
        #pragma unroll
        for (int ft = 0; ft < 16; ++ft)
            #pragma unroll
            for (int r = 0; r < 4; ++r)
                hp[r * EMBD + ft * 16] = f2bf(o[ft][r] * inv[r]);
    } else {
        int slot = (bh * 16 + (qt - 16)) * 2 + kc;
        float* Op = Opart + slot * 16384 + (w * 16 + quad * 4) * 256 + lane16;
        #pragma unroll
        for (int ft = 0; ft < 16; ++ft)
            #pragma unroll
            for (int r = 0; r < 4; ++r)
                Op[r * 256 + ft * 16] = o[ft][r];
        if (quad == 0) Lpart[slot * 64 + w * 16 + lane16] = lsum;
    }
}

// ---------------------------------------------------------------------------
// Kernel 4: combine split-k partials (unchanged).
// ---------------------------------------------------------------------------
__global__ __launch_bounds__(256) void combine_kernel(
    const float* __restrict__ Opart, const float* __restrict__ Lpart,
    unsigned short* __restrict__ heads)
{
    int t = blockIdx.x;
    int bh = t >> 4, qt = (t & 15) + 16;
    int s0 = t * 2, s1 = s0 + 1;
    int tid = threadIdx.x;
    int row = tid >> 2, fseg = (tid & 3) * 64;
    float l = Lpart[s0 * 64 + row] + Lpart[s1 * 64 + row];
    float inv = 1.f / l;
    const fx4* O0 = (const fx4*)(Opart + s0 * 16384 + row * 256 + fseg);
    const fx4* O1 = (const fx4*)(Opart + s1 * 16384 + row * 256 + fseg);
    int b = bh / 3, h = bh - (bh / 3) * 3;
    unsigned short* hp = heads + (b * SEQ + qt * 64 + row) * EMBD + h * HDIM + fseg;
    #pragma unroll
    for (int i = 0; i < 16; ++i) {
        fx4 v = O0[i] + O1[i];
        u16x4 pk;
        pk[0] = f2bf(v[0] * inv); pk[1] = f2bf(v[1] * inv);
        pk[2] = f2bf(v[2] * inv); pk[3] = f2bf(v[3] * inv);
        *(u16x4*)(hp + i * 4) = pk;
    }
}

// ---------------------------------------------------------------------------
// Kernel 5: output projection — same barrier-free B-resident structure.
// Block 256m x 64n, grid (32, 12); direct fp32 stores + bias.
// ---------------------------------------------------------------------------
__global__ __launch_bounds__(256, 3) void outproj_kernel(
    const unsigned short* __restrict__ A, const unsigned short* __restrict__ Wot,
    const float* __restrict__ bo, float* __restrict__ out)
{
    __shared__ alignas(16) unsigned short Bs[24576];

    int m0 = blockIdx.x * 256;
    int nb = blockIdx.y;
    const unsigned short* W = Wot + (nb * 64) * EMBD;

    int tid = threadIdx.x;
    int w = tid >> 6, ln = tid & 63;
    int lane16 = ln & 15, quad = ln >> 4;
    int mw = w * 64;

    fx4 acc[4][4];
    #pragma unroll
    for (int i = 0; i < 4; ++i)
        #pragma unroll
        for (int j = 0; j < 4; ++j) acc[i][j] = (fx4){0.f, 0.f, 0.f, 0.f};

    const unsigned short* Ap = A + (m0 + mw + lane16) * EMBD + quad * 8;

    u16x8 afc[4], afn[4];
    #pragma unroll
    for (int i = 0; i < 4; ++i) afc[i] = *(const u16x8*)(Ap + i * 16 * EMBD);

    int bsw = lane16 & 7;

    #pragma unroll
    for (int ph = 0; ph < 2; ++ph) {
        __syncthreads();
        #pragma unroll
        for (int jj = 0; jj < 12; ++jj) {
            int U = jj * 256 + tid;
            int row = U / 48;
            int slot = U - row * 48;
            int gu = (slot & ~7) | ((slot & 7) ^ (row & 7));
            gl_lds16(W + row * EMBD + ph * 384 + gu * 8, &Bs[U * 8]);
        }
        __syncthreads();

        #pragma unroll
        for (int kk = 0; kk < 12; ++kk) {
            int kbn = ph * 384 + kk * 32 + 32;
            if (kbn < EMBD) {
                #pragma unroll
                for (int i = 0; i < 4; ++i)
                    afn[i] = *(const u16x8*)(Ap + i * 16 * EMBD + kbn);
            }
            #pragma unroll
            for (int j = 0; j < 4; ++j) {
                int u = kk * 4 + quad;
                int slot = (u & ~7) | ((u & 7) ^ bsw);
                u16x8 bf = *(const u16x8*)&Bs[((j * 16 + lane16) * 48 + slot) * 8];
                #pragma unroll
                for (int i = 0; i < 4; ++i)
                    acc[i][j] = mfma16(afc[i], bf, acc[i][j]);
            }
            if (kbn < EMBD) {
                #pragma unroll
                for (int i = 0; i < 4; ++i) afc[i] = afn[i];
            }
        }
    }

    #pragma unroll
    for (int j = 0; j < 4; ++j) {
        int n = nb * 64 + j * 16 + lane16;
        float bias = bo[n];
        #pragma unroll
        for (int i = 0; i < 4; ++i) {
            int mb = m0 + mw + i * 16 + quad * 4;
            #pragma unroll
            for (int r = 0; r < 4; ++r)
                out[(size_t)(mb + r) * EMBD + n] = acc[i][j][r] + bias;
        }
    }
}

// ---------------------------------------------------------------------------
extern "C" void kernel_launch(void* const* d_in, const int* in_sizes, int n_in,
                              void* d_out, int out_size, void* d_ws, size_t ws_size,
                              hipStream_t stream) {
    const float* Ak = (const float*)d_in[0];
    const float* Av = (const float*)d_in[1];
    const float* Aq = (const float*)d_in[2];
    const float* Wk = (const float*)d_in[3];
    const float* Wv = (const float*)d_in[4];
    const float* Wq = (const float*)d_in[5];
    const float* Wo = (const float*)d_in[6];
    const float* bo = (const float*)d_in[7];
    float* out = (float*)d_out;

    char* base = (char*)d_ws;
    unsigned short* Wt    = (unsigned short*)(base);               // 3.54 MB
    unsigned short* Wot   = (unsigned short*)(base + 3538944);     // 1.18 MB
    unsigned short* Abf   = (unsigned short*)(base + 4718592);     // 37.75 MB
    unsigned short* Kg    = (unsigned short*)(base + 42467328);    // 12.58 MB
    unsigned short* Vg    = (unsigned short*)(base + 55050240);    // 12.58 MB
    unsigned short* Qg    = (unsigned short*)(base + 67633152);    // 12.58 MB
    unsigned short* heads = (unsigned short*)(base + 80216064);    // 12.58 MB
    // split-k partials overlay the Abf region (Abf dead after proj_kernel)
    float* Opart = (float*)(base + 4718592);                       // 25.17 MB
    float* Lpart = (float*)(base + 4718592 + 25165824);            // 98 KB

    castAw_kernel<<<dim3(9792), dim3(256), 0, stream>>>(
        Ak, Av, Aq, Wk, Wv, Wq, Wo, Abf, Wt, Wot);
    proj_kernel<<<dim3(32, 12, 3), dim3(256), 0, stream>>>(
        Abf, Wt, Kg, Vg, Qg);
    attn_kernel<<<dim3(576), dim3(256), 0, stream>>>(
        Kg, Vg, Qg, heads, Opart, Lpart);
    combine_kernel<<<dim3(192), dim3(256), 0, stream>>>(Opart, Lpart, heads);
    outproj_kernel<<<dim3(32, 12), dim3(256), 0, stream>>>(heads, Wot, bo, out);
}